// Round 13
// baseline (243.103 us; speedup 1.0000x reference)
//
#include <hip/hip_runtime.h>
#include <stdint.h>

// PressureLSTM: B=4096, T=512, F=32, H=32, gates=128 (i,f,g,o).
// Swapped-MFMA, permuted gate index pg = e*4 + gtype (verified r5-r11):
//   mfma(A=W', B=X^T/H^T); lane's 4 acc regs = i,f,g,o of
//   (element e=4*wv+q, batch row col) -> lane-local cell update.
// r13 (= r12 with the macro-pragma build error fixed):
//   XS LDS ELIMINATED. The x B-fragment (x[b0+col][t][k0..k0+7]) is loaded
//   DIRECTLY from global per lane (2x dwordx4, 128B-coalesced per row group;
//   8-wave duplicates hit L1). 3-step register FIFO covers HBM latency.
//   -> LDS traffic per step halves (only hs remains: 16B read + 2B write per
//   lane); critical ds_read(ah) no longer queues behind xs reads; xs bank
//   conflicts gone; stager role deleted.
//   Critical path: barrier -> ds_read(ah) -> mfma(whh,ah,C=a1c) -> act -> write.
//   a1c(t+1) = mfma(wih, cvt(x(t+1)), bias) computed in the activation shadow.
//   Single-rcp fused c-update (7 trans/cell), c clamped to +-16, weights
//   pre-scaled by -log2e (i,f,o) / +2log2e (g).

typedef _Float16 half8 __attribute__((ext_vector_type(8)));
typedef __attribute__((ext_vector_type(4))) float float4v;

#define T_LEN 512
#define B_ALL 4096
#define ROWS 16
#define NBLK (B_ALL / ROWS)   // 256 blocks -> 1 block/CU
#define P 40                  // f16 per LDS row (80 B pitch, b128-aligned)

__global__ __launch_bounds__(512, 2) void lstm_fused_kernel(
    const float* __restrict__ x,     // [B, T, 32]
    const float* __restrict__ W_ih,  // [128, 32]
    const float* __restrict__ W_hh,  // [128, 32]
    const float* __restrict__ b_ih,  // [128]
    const float* __restrict__ b_hh,  // [128]
    const float* __restrict__ W_fc,  // [1, 32]
    const float* __restrict__ b_fc,  // [1]
    float* __restrict__ out)         // [B]
{
    const int tid  = threadIdx.x;    // 0..511
    const int wv   = tid >> 6;       // wave 0..7 (gate tile wv)
    const int lane = tid & 63;
    const int col  = lane & 15;      // batch row within tile (all real)
    const int q    = lane >> 4;      // 0..3
    const int k0   = q * 8;
    const int b0   = blockIdx.x * ROWS;
    const int e    = 4 * wv + q;     // this lane's h element (0..31)

    __shared__ __align__(16) _Float16 hs[2][ROWS][P];

    // ---- A-fragment weights, single f16 (RNE), pre-scaled per gate type:
    // lane holds W'[pg=16wv+col][k0..k0+7]; pg=e'*4+gt, e'=4wv+(col>>2), gt=col&3
    half8 wih, whh;
    {
        const int gt   = col & 3;
        const int gmem = gt * 32 + (4 * wv + (col >> 2));
        const float gs = (gt == 2) ? 2.88539008f : -1.44269504f;
        const float* wr = W_ih + gmem * 32 + k0;
        const float* hr = W_hh + gmem * 32 + k0;
        #pragma unroll
        for (int i = 0; i < 8; ++i) {
            wih[i] = (_Float16)(wr[i] * gs);
            whh[i] = (_Float16)(hr[i] * gs);
        }
    }
    // bias for acc reg r: gate type r of element e, same pre-scale
    float4v bias4;
    #pragma unroll
    for (int r = 0; r < 4; ++r) {
        const float gsr = (r == 2) ? 2.88539008f : -1.44269504f;
        bias4[r] = (b_ih[r * 32 + e] + b_hh[r * 32 + e]) * gsr;
    }

    float c = 0.f;

    // ---- per-lane x source: this lane's own B-fragment rows
    const float* xrow = x + (size_t)(b0 + col) * (T_LEN * 32) + k0;

    // prologue: a1c for t=0; FIFO xa=x(1), xb=x(2), xc=x(3); h(-1)=0
    float4v a1c;
    {
        float4v v0 = *(const float4v*)(xrow);
        float4v v1 = *(const float4v*)(xrow + 4);
        half8 ax0;
        ax0[0] = (_Float16)v0[0]; ax0[1] = (_Float16)v0[1];
        ax0[2] = (_Float16)v0[2]; ax0[3] = (_Float16)v0[3];
        ax0[4] = (_Float16)v1[0]; ax0[5] = (_Float16)v1[1];
        ax0[6] = (_Float16)v1[2]; ax0[7] = (_Float16)v1[3];
        a1c = __builtin_amdgcn_mfma_f32_16x16x32_f16(wih, ax0, bias4, 0, 0, 0);
    }
    float4v xa0 = *(const float4v*)(xrow + 1 * 32);
    float4v xa1 = *(const float4v*)(xrow + 1 * 32 + 4);
    float4v xb0 = *(const float4v*)(xrow + 2 * 32);
    float4v xb1 = *(const float4v*)(xrow + 2 * 32 + 4);
    float4v xc0 = *(const float4v*)(xrow + 3 * 32);
    float4v xc1 = *(const float4v*)(xrow + 3 * 32 + 4);

    // h(-1) = 0: 512 threads cover 16 rows x 32 elems
    hs[0][tid >> 5][tid & 31] = (_Float16)0.f;
    __syncthreads();

    // step t (hs parity PPAR=t&1): reads hs[PPAR], writes hs[PPAR^1].
    // FIFO: converts xa=x(t+1); shifts xb->xa, xc->xb; loads xc=x(t+4).
    #define STEP(PPAR, TT)                                                      \
    {                                                                           \
        const half8 ah = *(const half8*)&hs[PPAR][col][k0];   /* critical */    \
        const float4v acc =                                                     \
            __builtin_amdgcn_mfma_f32_16x16x32_f16(whh, ah, a1c, 0, 0, 0);      \
        /* next step's x-side acc (off critical path) */                        \
        half8 axn;                                                              \
        axn[0] = (_Float16)xa0[0]; axn[1] = (_Float16)xa0[1];                   \
        axn[2] = (_Float16)xa0[2]; axn[3] = (_Float16)xa0[3];                   \
        axn[4] = (_Float16)xa1[0]; axn[5] = (_Float16)xa1[1];                   \
        axn[6] = (_Float16)xa1[2]; axn[7] = (_Float16)xa1[3];                   \
        a1c = __builtin_amdgcn_mfma_f32_16x16x32_f16(wih, axn, bias4, 0, 0, 0); \
        xa0 = xb0; xa1 = xb1; xb0 = xc0; xb1 = xc1;                             \
        {                                                                       \
            int tn = (TT) + 4; if (tn >= T_LEN) tn = T_LEN - 1;                 \
            xc0 = *(const float4v*)(xrow + (size_t)tn * 32);                    \
            xc1 = *(const float4v*)(xrow + (size_t)tn * 32 + 4);                \
        }                                                                       \
        /* fused activations (single-rcp c-update):                          */ \
        /* c' = [c(1+Ai)(1+Bg) + (Bg-1)(1+Af)] * rcp((1+Af)(1+Ai)(1+Bg))    */  \
        const float Ai = __builtin_amdgcn_exp2f(acc[0]);                        \
        const float Af = __builtin_amdgcn_exp2f(acc[1]);                        \
        const float Bg = __builtin_amdgcn_exp2f(acc[2]);                        \
        const float Ao = __builtin_amdgcn_exp2f(acc[3]);                        \
        const float pI = 1.0f + Ai;                                             \
        const float pG = 1.0f + Bg;                                             \
        const float pF = 1.0f + Af;                                             \
        const float pIG = pI * pG;                                              \
        const float num = c * pIG + (Bg - 1.0f) * pF;                           \
        c = num * __builtin_amdgcn_rcpf(pF * pIG);                              \
        const float cc = fminf(fmaxf(c, -16.0f), 16.0f);                        \
        const float C2 = __builtin_amdgcn_exp2f(cc * 2.88539008f);              \
        const float r3 = __builtin_amdgcn_rcpf((1.0f + Ao) * (1.0f + C2));      \
        const float hv = (C2 - 1.0f) * r3;                                      \
        hs[PPAR ^ 1][col][e] = (_Float16)hv;                                    \
        __syncthreads();                                                        \
    }

    for (int t = 0; t < T_LEN; t += 2) {
        STEP(0, t)
        STEP(1, t + 1)
    }
    #undef STEP

    // ---- epilogue: h(511) was written to hs[0] (step 511 has parity 1)
    if (tid < ROWS) {
        float s = b_fc[0];
        #pragma unroll
        for (int cc2 = 0; cc2 < 32; ++cc2) {
            s += (float)hs[0][tid][cc2] * W_fc[cc2];
        }
        out[b0 + tid] = s;
    }
}

extern "C" void kernel_launch(void* const* d_in, const int* in_sizes, int n_in,
                              void* d_out, int out_size, void* d_ws, size_t ws_size,
                              hipStream_t stream) {
    const float* x    = (const float*)d_in[0];
    const float* W_ih = (const float*)d_in[1];
    const float* W_hh = (const float*)d_in[2];
    const float* b_ih = (const float*)d_in[3];
    const float* b_hh = (const float*)d_in[4];
    const float* W_fc = (const float*)d_in[5];
    const float* b_fc = (const float*)d_in[6];
    float* out = (float*)d_out;

    lstm_fused_kernel<<<dim3(NBLK), dim3(512), 0, stream>>>(
        x, W_ih, W_hh, b_ih, b_hh, W_fc, b_fc, out);
}

// Round 14
// 149.975 us; speedup vs baseline: 1.6210x; 1.6210x over previous
//
#include <hip/hip_runtime.h>
#include <stdint.h>

// PressureLSTM: B=4096, T=512, F=32, H=32, gates=128 (i,f,g,o).
// Swapped-MFMA, permuted gate index pg = e*4 + gtype (verified r5-r11):
//   mfma(A=W', B=X^T/H^T); lane's 4 acc regs = i,f,g,o of
//   (element e=4*wv+q, batch row col) -> lane-local cell update.
// r14 (from r11 base = 137us; r13's VMEM-direct x regressed and is reverted):
//   RAW-BARRIER PIPELINE: __syncthreads() drains vmcnt(0) every step (the
//   compiler emits s_waitcnt vmcnt(0) lgkmcnt(0) before s_barrier), which
//   serialized the global x prefetch into each step. Replace the loop barrier
//   with asm lgkmcnt(0) + s_barrier (LDS visibility only); x loads now stay
//   in flight across steps, waited by compiler-counted vmcnt at the cvt use
//   3 steps later. 3-deep x register FIFO (slack ~3 steps > HBM latency);
//   LDS stage-write issued BEFORE the new global load; sched_barrier(0)
//   after s_barrier (guide rule #18); only the critical ds_read(ah) sits in
//   the post-barrier LDS pile (axn read after the critical MFMA).
//   x staged through LDS xs[4] ring as f16 (one coalesced dword/thread);
//   f16 weights (RNE), C-operand x-projection, single-rcp fused c-update
//   (7 trans/cell), c clamped +-16, weights pre-scaled by -log2e / +2log2e.

typedef _Float16 half8 __attribute__((ext_vector_type(8)));
typedef __attribute__((ext_vector_type(4))) float float4v;

#define T_LEN 512
#define B_ALL 4096
#define ROWS 16
#define NBLK (B_ALL / ROWS)   // 256 blocks -> 1 block/CU
#define P 40                  // f16 per LDS row (80 B pitch, b128-aligned)

__global__ __launch_bounds__(512, 2) void lstm_fused_kernel(
    const float* __restrict__ x,     // [B, T, 32]
    const float* __restrict__ W_ih,  // [128, 32]
    const float* __restrict__ W_hh,  // [128, 32]
    const float* __restrict__ b_ih,  // [128]
    const float* __restrict__ b_hh,  // [128]
    const float* __restrict__ W_fc,  // [1, 32]
    const float* __restrict__ b_fc,  // [1]
    float* __restrict__ out)         // [B]
{
    const int tid  = threadIdx.x;    // 0..511
    const int wv   = tid >> 6;       // wave 0..7 (gate tile wv)
    const int lane = tid & 63;
    const int col  = lane & 15;      // batch row within tile (all real)
    const int q    = lane >> 4;      // 0..3
    const int k0   = q * 8;
    const int b0   = blockIdx.x * ROWS;
    const int e    = 4 * wv + q;     // this lane's h element (0..31)

    __shared__ __align__(16) _Float16 hs[2][ROWS][P];
    __shared__ __align__(16) _Float16 xs[4][ROWS][P];

    // ---- A-fragment weights, single f16 (RNE), pre-scaled per gate type:
    // lane holds W'[pg=16wv+col][k0..k0+7]; pg=e'*4+gt, e'=4wv+(col>>2), gt=col&3
    half8 wih, whh;
    {
        const int gt   = col & 3;
        const int gmem = gt * 32 + (4 * wv + (col >> 2));
        const float gs = (gt == 2) ? 2.88539008f : -1.44269504f;
        const float* wr = W_ih + gmem * 32 + k0;
        const float* hr = W_hh + gmem * 32 + k0;
        #pragma unroll
        for (int i = 0; i < 8; ++i) {
            wih[i] = (_Float16)(wr[i] * gs);
            whh[i] = (_Float16)(hr[i] * gs);
        }
    }
    // bias for acc reg r: gate type r of element e, same pre-scale
    float4v bias4;
    #pragma unroll
    for (int r = 0; r < 4; ++r) {
        const float gsr = (r == 2) ? 2.88539008f : -1.44269504f;
        bias4[r] = (b_ih[r * 32 + e] + b_hh[r * 32 + e]) * gsr;
    }

    float c = 0.f;

    // ---- x staging: all 512 threads cover 16 rows x 32 k, one float each
    const int sr = tid >> 5;         // staged row 0..15
    const int sk = tid & 31;         // k element
    const float* xsrc = x + ((size_t)(b0 + sr) * T_LEN) * 32 + sk;

    // prologue: prime xs[0..2] with x(0..2); h(-1)=0; FIFO xA..xC = x(3..5)
    float xA, xB, xC;
    {
        xs[0][sr][sk] = (_Float16)xsrc[0];
        xs[1][sr][sk] = (_Float16)xsrc[32];
        xs[2][sr][sk] = (_Float16)xsrc[64];
        hs[0][sr][sk] = (_Float16)0.f;
        xA = xsrc[3 * 32];
        xB = xsrc[4 * 32];
        xC = xsrc[5 * 32];
    }
    __syncthreads();

    // a1c for t=0 (x-side acc, bias folded as C)
    float4v a1c;
    {
        const half8 ax0 = *(const half8*)&xs[0][col][k0];
        a1c = __builtin_amdgcn_mfma_f32_16x16x32_f16(wih, ax0, bias4, 0, 0, 0);
    }

    // step t (hs parity PPAR=t&1): reads hs[PPAR], writes hs[PPAR^1].
    // xs ring: reads xs[(t+1)&3] (next-step x), writes xs[(t+3)&3] from xA;
    // FIFO shift xA<-xB<-xC; loads xC = x(t+6). Loop barrier = raw s_barrier
    // with lgkmcnt(0) only -> global loads stay in flight across steps.
    #define STEP(PPAR, TT)                                                      \
    {                                                                           \
        const half8 ah = *(const half8*)&hs[PPAR][col][k0];   /* critical */    \
        const float4v acc =                                                     \
            __builtin_amdgcn_mfma_f32_16x16x32_f16(whh, ah, a1c, 0, 0, 0);      \
        /* next step's x-side acc (off critical path) */                        \
        const half8 axn = *(const half8*)&xs[((TT) + 1) & 3][col][k0];          \
        a1c = __builtin_amdgcn_mfma_f32_16x16x32_f16(wih, axn, bias4, 0, 0, 0); \
        /* stage x(TT+3) -> xs ring (cvt+write BEFORE new load so the */        \
        /* compiler's vmcnt wait here counts only old loads) */                 \
        xs[((TT) + 3) & 3][sr][sk] = (_Float16)xA;                              \
        xA = xB; xB = xC;                                                       \
        {                                                                       \
            int tn = (TT) + 6; if (tn >= T_LEN) tn = T_LEN - 1;                 \
            xC = xsrc[(size_t)tn * 32];                                         \
        }                                                                       \
        /* fused activations (single-rcp c-update):                          */ \
        /* c' = [c(1+Ai)(1+Bg) + (Bg-1)(1+Af)] * rcp((1+Af)(1+Ai)(1+Bg))    */  \
        const float Ai = __builtin_amdgcn_exp2f(acc[0]);                        \
        const float Af = __builtin_amdgcn_exp2f(acc[1]);                        \
        const float Bg = __builtin_amdgcn_exp2f(acc[2]);                        \
        const float Ao = __builtin_amdgcn_exp2f(acc[3]);                        \
        const float pI = 1.0f + Ai;                                             \
        const float pG = 1.0f + Bg;                                             \
        const float pF = 1.0f + Af;                                             \
        const float pIG = pI * pG;                                              \
        const float num = c * pIG + (Bg - 1.0f) * pF;                           \
        c = num * __builtin_amdgcn_rcpf(pF * pIG);                              \
        const float cc = fminf(fmaxf(c, -16.0f), 16.0f);                        \
        const float C2 = __builtin_amdgcn_exp2f(cc * 2.88539008f);              \
        const float r3 = __builtin_amdgcn_rcpf((1.0f + Ao) * (1.0f + C2));      \
        const float hv = (C2 - 1.0f) * r3;                                      \
        hs[PPAR ^ 1][col][e] = (_Float16)hv;                                    \
        /* LDS-only barrier: h/xs writes retired, vmcnt NOT drained */          \
        asm volatile("s_waitcnt lgkmcnt(0)" ::: "memory");                      \
        __builtin_amdgcn_s_barrier();                                           \
        __builtin_amdgcn_sched_barrier(0);                                      \
    }

    for (int t = 0; t < T_LEN; t += 2) {
        STEP(0, t)
        STEP(1, t + 1)
    }
    #undef STEP

    // ---- epilogue: h(511) was written to hs[0] (step 511 has parity 1)
    if (tid < ROWS) {
        float s = b_fc[0];
        #pragma unroll
        for (int cc2 = 0; cc2 < 32; ++cc2) {
            s += (float)hs[0][tid][cc2] * W_fc[cc2];
        }
        out[b0 + tid] = s;
    }
}

extern "C" void kernel_launch(void* const* d_in, const int* in_sizes, int n_in,
                              void* d_out, int out_size, void* d_ws, size_t ws_size,
                              hipStream_t stream) {
    const float* x    = (const float*)d_in[0];
    const float* W_ih = (const float*)d_in[1];
    const float* W_hh = (const float*)d_in[2];
    const float* b_ih = (const float*)d_in[3];
    const float* b_hh = (const float*)d_in[4];
    const float* W_fc = (const float*)d_in[5];
    const float* b_fc = (const float*)d_in[6];
    float* out = (float*)d_out;

    lstm_fused_kernel<<<dim3(NBLK), dim3(512), 0, stream>>>(
        x, W_ih, W_hh, b_ih, b_hh, W_fc, b_fc, out);
}